// Round 3
// baseline (50.563 us; speedup 1.0000x reference)
//
#include <hip/hip_runtime.h>
#include <hip/hip_bf16.h>
#include <hip/hip_fp16.h>
#include <stdint.h>

#define IN_F 2048
#define OUT_F 128
#define KD 32
#define NR 256
#define OC 2176          // IN_F + OUT_F
#define OD 4096          // OUT_F * KD

typedef __bf16 bf16x8 __attribute__((ext_vector_type(8)));
typedef float f32x4 __attribute__((ext_vector_type(4)));
typedef _Float16 half2v __attribute__((ext_vector_type(2)));

// ---------------------------------------------------------------------------
// Prep: copy x -> out[:, 0:2048] and write xb2 = bf16(x) in MFMA A-frag order:
//   chunk q = (h*4 + fg)*256 + row   holds x[row][q>>8 * 8 .. +8]  (h = k/32*... :
//   k0 = (q>>8)*8, i.e. h = k0/32, fg = (k0%32)/8)
// ---------------------------------------------------------------------------
__global__ __launch_bounds__(256) void prep_kernel(const float* __restrict__ x,
                                                   float* __restrict__ out,
                                                   __bf16* __restrict__ xb2) {
    const int q   = blockIdx.x * 256 + threadIdx.x;   // 0..65535
    const int row = q & 255;
    const int k0  = (q >> 8) << 3;

    const float* src = &x[row * IN_F + k0];
    float4 v0 = *reinterpret_cast<const float4*>(src);
    float4 v1 = *reinterpret_cast<const float4*>(src + 4);

    *reinterpret_cast<float4*>(&out[row * OC + k0])     = v0;
    *reinterpret_cast<float4*>(&out[row * OC + k0 + 4]) = v1;

    bf16x8 p = { (__bf16)v0.x, (__bf16)v0.y, (__bf16)v0.z, (__bf16)v0.w,
                 (__bf16)v1.x, (__bf16)v1.y, (__bf16)v1.z, (__bf16)v1.w };
    *reinterpret_cast<bf16x8*>(&xb2[(size_t)q * 8]) = p;
}

// ---------------------------------------------------------------------------
// GEMM (register-direct, no LDS): Mt[o][n] = sum_k x[n][k]*T[k][o], split-K 2.
// Wave tile: 32 n x 32 o. Block = 4 waves (o-adjacent). grid (32, 8, 2).
// Per half-step (32 k): A 2x bf16x8 from xb2 (frag order), B 16 dword from T.
// 3-deep register prefetch via 4 rotating frag sets; compiler tracks waits.
// ---------------------------------------------------------------------------
struct Frag {
    bf16x8 a0, a1;      // mi = 0,1
    float  b[2][8];     // [oi][i]
};

__device__ __forceinline__ Frag load_frag(const __bf16* __restrict__ xb2,
                                          const float* __restrict__ Tm,
                                          int h, int n0, int o0, int fr, int fg) {
    Frag f;
    const __bf16* abase = xb2 + ((size_t)(h * 4 + fg) * 256 + n0 + fr) * 8;
    f.a0 = *reinterpret_cast<const bf16x8*>(abase);
    f.a1 = *reinterpret_cast<const bf16x8*>(abase + 16 * 8);
    const float* bbase = Tm + (size_t)(h * 32 + fg * 8) * OD + o0 + fr;
    #pragma unroll
    for (int i = 0; i < 8; ++i) {
        f.b[0][i] = bbase[(size_t)i * OD];
        f.b[1][i] = bbase[(size_t)i * OD + 16];
    }
    return f;
}

__device__ __forceinline__ void comp(const Frag& f, f32x4 acc[2][2]) {
    #pragma unroll
    for (int oi = 0; oi < 2; ++oi) {
        bf16x8 bb = { (__bf16)f.b[oi][0], (__bf16)f.b[oi][1],
                      (__bf16)f.b[oi][2], (__bf16)f.b[oi][3],
                      (__bf16)f.b[oi][4], (__bf16)f.b[oi][5],
                      (__bf16)f.b[oi][6], (__bf16)f.b[oi][7] };
        acc[0][oi] = __builtin_amdgcn_mfma_f32_16x16x32_bf16(f.a0, bb, acc[0][oi], 0, 0, 0);
        acc[1][oi] = __builtin_amdgcn_mfma_f32_16x16x32_bf16(f.a1, bb, acc[1][oi], 0, 0, 0);
    }
}

__global__ __launch_bounds__(256) void gemm_kernel(const __bf16* __restrict__ xb2,
                                                   const float* __restrict__ Tm,
                                                   float* __restrict__ Mt) {
    const int tid  = threadIdx.x;
    const int lane = tid & 63;
    const int w    = tid >> 6;
    const int fr   = lane & 15;
    const int fg   = lane >> 4;
    const int o0   = blockIdx.x * 128 + w * 32;
    const int n0   = blockIdx.y * 32;
    const int bz   = blockIdx.z;
    const int h0   = bz * 32;          // 32 half-steps per split
    float* dst = Mt + (size_t)bz * OD * NR;

    f32x4 acc[2][2] = {};

    Frag s0 = load_frag(xb2, Tm, h0 + 0, n0, o0, fr, fg);
    Frag s1 = load_frag(xb2, Tm, h0 + 1, n0, o0, fr, fg);
    Frag s2 = load_frag(xb2, Tm, h0 + 2, n0, o0, fr, fg);

    for (int h = 0; h < 28; h += 4) {
        Frag s3 = load_frag(xb2, Tm, h0 + h + 3, n0, o0, fr, fg);
        comp(s0, acc);
        s0 = load_frag(xb2, Tm, h0 + h + 4, n0, o0, fr, fg);
        comp(s1, acc);
        s1 = load_frag(xb2, Tm, h0 + h + 5, n0, o0, fr, fg);
        comp(s2, acc);
        s2 = load_frag(xb2, Tm, h0 + h + 6, n0, o0, fr, fg);
        comp(s3, acc);
    }
    {
        Frag s3 = load_frag(xb2, Tm, h0 + 31, n0, o0, fr, fg);
        comp(s0, acc);
        comp(s1, acc);
        comp(s2, acc);
        comp(s3, acc);
    }

    // epilogue: D[row=n][col=o] -> dst[o*256 + n]; 4 consecutive n per lane
    #pragma unroll
    for (int mi = 0; mi < 2; ++mi) {
        #pragma unroll
        for (int oi = 0; oi < 2; ++oi) {
            const int o = o0 + oi * 16 + fr;
            *reinterpret_cast<f32x4*>(&dst[(size_t)o * NR + n0 + mi * 16 + fg * 4]) = acc[mi][oi];
        }
    }
}

// ---------------------------------------------------------------------------
// Pairwise: o_b[j,f] = sum_i exp(-sum_d |M[i,f,d]-M[j,f,d]|), packed f16.
// grid (128 f, 4 j-quarters); 256 threads; wave wid owns i in [wid*64,+64).
// Mf rows staged as 16 packed-f16 u32 (summed split-K partials).
// ---------------------------------------------------------------------------
__global__ __launch_bounds__(256, 2) void pairwise_kernel(const float* __restrict__ Mt0,
                                                          const float* __restrict__ Mt1,
                                                          float* __restrict__ out) {
    __shared__ uint32_t Mf[256][18];   // 16 used + pad (rows 8B-aligned, b64 reads ok)
    __shared__ float part[4][64];

    const int f    = blockIdx.x;
    const int jq   = blockIdx.y;
    const int tid  = threadIdx.x;
    const int lane = tid & 63;
    const int wid  = tid >> 6;

    #pragma unroll
    for (int d2 = 0; d2 < 16; ++d2) {
        float v0 = Mt0[(f * KD + 2 * d2)     * NR + tid] + Mt1[(f * KD + 2 * d2)     * NR + tid];
        float v1 = Mt0[(f * KD + 2 * d2 + 1) * NR + tid] + Mt1[(f * KD + 2 * d2 + 1) * NR + tid];
        half2v h = { (_Float16)v0, (_Float16)v1 };
        Mf[tid][d2] = __builtin_bit_cast(uint32_t, h);
    }
    __syncthreads();

    const int j = jq * 64 + lane;
    uint32_t mj[16];
    #pragma unroll
    for (int p = 0; p < 16; ++p) mj[p] = Mf[j][p];

    const half2v ones = { (_Float16)1.f, (_Float16)1.f };
    float acc = 0.f;
    for (int ii = 0; ii < 64; ++ii) {
        const int i = wid * 64 + ii;
        float norm = 0.f;
        #pragma unroll
        for (int p = 0; p < 16; ++p) {
            half2v a = __builtin_bit_cast(half2v, Mf[i][p]);
            half2v d = a - __builtin_bit_cast(half2v, mj[p]);
            uint32_t ad = __builtin_bit_cast(uint32_t, d) & 0x7fff7fffu;
#if __has_builtin(__builtin_amdgcn_fdot2)
            norm = __builtin_amdgcn_fdot2(__builtin_bit_cast(half2v, ad), ones, norm, false);
#else
            half2v adv = __builtin_bit_cast(half2v, ad);
            norm += (float)adv[0] + (float)adv[1];
#endif
        }
        acc += __expf(-norm);
    }

    part[wid][lane] = acc;
    __syncthreads();
    if (tid < 64) {
        float s = part[0][tid] + part[1][tid] + part[2][tid] + part[3][tid];
        const int jj = jq * 64 + tid;
        out[jj * OC + IN_F + f] = s;
    }
}

extern "C" void kernel_launch(void* const* d_in, const int* in_sizes, int n_in,
                              void* d_out, int out_size, void* d_ws, size_t ws_size,
                              hipStream_t stream) {
    const float* x  = (const float*)d_in[0];   // [256, 2048] f32
    const float* Tm = (const float*)d_in[1];   // [2048, 4096] f32
    float* out = (float*)d_out;                // [256, 2176] f32
    char*  ws  = (char*)d_ws;

    __bf16* xb2 = (__bf16*)ws;                          // 1 MB frag-ordered bf16 x
    float*  Mt0 = (float*)(ws + (1 << 20));             // 4 MB split-K partial 0
    float*  Mt1 = (float*)(ws + (1 << 20) + (4 << 20)); // 4 MB split-K partial 1

    prep_kernel<<<dim3(256), 256, 0, stream>>>(x, out, xb2);
    gemm_kernel<<<dim3(32, 8, 2), 256, 0, stream>>>(xb2, Tm, Mt0);
    pairwise_kernel<<<dim3(128, 4), 256, 0, stream>>>(Mt0, Mt1, out);
}